// Round 10
// baseline (6498.655 us; speedup 1.0000x reference)
//
#include <hip/hip_runtime.h>

#define TMAX 8192
#define H 128

typedef float v2f __attribute__((ext_vector_type(2)));

// rcp-based activations (v_rcp_f32, ~1 ulp) — proven win (round 7).
__device__ __forceinline__ float sigf(float x) {
    return __builtin_amdgcn_rcpf(1.f + __expf(-x));
}
__device__ __forceinline__ float tanhf_fast(float x) {
    return fmaf(2.f, __builtin_amdgcn_rcpf(1.f + __expf(-2.f * x)), -1.f);
}

// Sum across the 8 lanes {quad} x {lane^32}: two DPP quad_perm rounds
// (lane bits 0,1) + v_permlane32_swap (bit 5). All VALU — no DS pipe.
__device__ __forceinline__ float rsum8(float v) {
    int s = __builtin_amdgcn_update_dpp(0, __float_as_int(v), 0xB1, 0xF, 0xF, true); // xor1
    v += __int_as_float(s);
    s = __builtin_amdgcn_update_dpp(0, __float_as_int(v), 0x4E, 0xF, 0xF, true);     // xor2
    v += __int_as_float(s);
    float d = v;
    // d_hi <-> v_lo: after, d = dup(v_lo-sum), v = dup(v_hi-sum); d+v = full sum.
    asm("v_permlane32_swap_b32 %0, %1" : "+v"(d), "+v"(v));
    return d + v;
}

// One block, 1024 threads = 16 waves (4/SIMD).
// Thread t: lane l=t&63, k-slice o = (l&3)|((l>>3)&4) (lane bits 0,1,5),
// j = (t>>6)*8 + ((l>>2)&7). Owns all 4 gate rows x 16-wide k-slice = 64
// weights (fits 128-reg budget at 4 waves/EU; AGPR parking is FREE for
// compiler-emitted FMA reads — round 0/8/9 triangulation).
//
// ROUND 10: round 8's 1350 cyc/step = ~500 issue + ~850 UNHIDDEN latency
// (2 barrier-locked waves/SIMD stall together on ds_read/act chains).
// 4 waves/SIMD staggers the stalls; issue rises to ~816 but overlaps.
// Reverted round 9's asm pk_fma (it forced accvgpr_read copies, +160 cyc).
__attribute__((amdgpu_waves_per_eu(4, 4)))
__global__ __launch_bounds__(1024)
void lstm_seq_kernel(const float* __restrict__ x,
                     const float* __restrict__ Wih,
                     const float* __restrict__ Whh,
                     const float* __restrict__ bih,
                     const float* __restrict__ bhh,
                     const float* __restrict__ Wlin,
                     const float* __restrict__ blin,
                     const float* __restrict__ h0,
                     const float* __restrict__ c0,
                     float* __restrict__ out,
                     int T)
{
    __shared__ float  x_s[TMAX];      // 32 KB
    // Interleaved h (float4 units): slot(p4,o) = p4*8 + o, element e:
    // o=e>>4, p4=(e&15)>>2, comp=e&3 -> float idx 32*p4 + 4*o + comp.
    // o-groups read disjoint bank quads (addr = slot*16B -> banks 4o..4o+3),
    // same-o lanes broadcast: conflict-free.
    __shared__ float4 hA[32], hB[32];

    const int t = threadIdx.x;        // 0..1023
    const int l = t & 63;
    const int o = (l & 3) | ((l >> 3) & 4);
    const int j = (t >> 6) * 8 + ((l >> 2) & 7);

    for (int idx = t; idx < T; idx += 1024) x_s[idx] = x[idx];

    const float4* pi = (const float4*)(Whh + (j      ) * H + o * 16);
    const float4* pf = (const float4*)(Whh + (j + 128) * H + o * 16);
    const float4* pg = (const float4*)(Whh + (j + 256) * H + o * 16);
    const float4* po = (const float4*)(Whh + (j + 384) * H + o * 16);

    // One-shot weight loads (asm volatile: issued exactly once, not remat-able).
#define ASMLD4(dst, base, n) \
    { const float4* _a = (base) + (n); \
      asm volatile("global_load_dwordx4 %0, %1, off" : "=v"(dst) : "v"(_a)); }
    float4 wi0, wi1, wi2, wi3;
    float4 wf0, wf1, wf2, wf3;
    float4 wg0, wg1, wg2, wg3;
    float4 wo0, wo1, wo2, wo3;
#define LOADW(n) \
    ASMLD4(wi##n, pi, n) ASMLD4(wf##n, pf, n) ASMLD4(wg##n, pg, n) ASMLD4(wo##n, po, n)
    LOADW(0) LOADW(1) LOADW(2) LOADW(3)
#undef LOADW
#undef ASMLD4

#define ASMLD1(dst, ptr) \
    { const float* _a = (ptr); \
      asm volatile("global_load_dword %0, %1, off" : "=v"(dst) : "v"(_a)); }
    float wxi, wxf, wxg, wxo, vbi, vbf, vbg, vbo, vb2i, vb2f, vb2g, vb2o;
    ASMLD1(wxi, Wih + j)        ASMLD1(wxf, Wih + j + 128)
    ASMLD1(wxg, Wih + j + 256)  ASMLD1(wxo, Wih + j + 384)
    ASMLD1(vbi, bih + j)        ASMLD1(vbf, bih + j + 128)
    ASMLD1(vbg, bih + j + 256)  ASMLD1(vbo, bih + j + 384)
    ASMLD1(vb2i, bhh + j)       ASMLD1(vb2f, bhh + j + 128)
    ASMLD1(vb2g, bhh + j + 256) ASMLD1(vb2o, bhh + j + 384)
#undef ASMLD1

    asm volatile("s_waitcnt vmcnt(0)");
    __builtin_amdgcn_sched_barrier(0);   // rule #18

    // Split each float4 into aligned v2f halves for packed FMA.
#define SPLIT(G,n) \
    v2f G##a##n = {w##G##n.x, w##G##n.y}; \
    v2f G##b##n = {w##G##n.z, w##G##n.w};
    SPLIT(i,0) SPLIT(i,1) SPLIT(i,2) SPLIT(i,3)
    SPLIT(f,0) SPLIT(f,1) SPLIT(f,2) SPLIT(f,3)
    SPLIT(g,0) SPLIT(g,1) SPLIT(g,2) SPLIT(g,3)
    SPLIT(o,0) SPLIT(o,1) SPLIT(o,2) SPLIT(o,3)
#undef SPLIT

    const bool lead = (o == 0);
    if (!lead) { wxi = 0.f; wxf = 0.f; wxg = 0.f; wxo = 0.f; }
    const float bi_ = lead ? vbi + vb2i : 0.f;
    const float bf_ = lead ? vbf + vb2f : 0.f;
    const float bg_ = lead ? vbg + vb2g : 0.f;
    const float bo_ = lead ? vbo + vb2o : 0.f;

    float c = c0[j];                  // replicated across the 8 lanes of j's group

    if (t < H) {
        const int fi = 32 * ((t & 15) >> 2) + 4 * (t >> 4) + (t & 3);
        ((float*)hA)[fi] = h0[t];
    }
    const int widx = 32 * ((j & 15) >> 2) + 4 * (j >> 4) + (j & 3);
    __syncthreads();

#define DO(n, hrd) { \
        const float4 h4 = hrd[n * 8 + o]; \
        const v2f hab = {h4.x, h4.y}; \
        const v2f hcd = {h4.z, h4.w}; \
        aci = __builtin_elementwise_fma(i##a##n, hab, aci); \
        acf = __builtin_elementwise_fma(f##a##n, hab, acf); \
        acg = __builtin_elementwise_fma(g##a##n, hab, acg); \
        aco = __builtin_elementwise_fma(o##a##n, hab, aco); \
        aci = __builtin_elementwise_fma(i##b##n, hcd, aci); \
        acf = __builtin_elementwise_fma(f##b##n, hcd, acf); \
        acg = __builtin_elementwise_fma(g##b##n, hcd, acg); \
        aco = __builtin_elementwise_fma(o##b##n, hcd, aco); }

#define STEP(hrd, hwr, sidx) { \
        const float xv = x_s[sidx]; \
        v2f aci = {fmaf(xv, wxi, bi_), 0.f}; \
        v2f acf = {fmaf(xv, wxf, bf_), 0.f}; \
        v2f acg = {fmaf(xv, wxg, bg_), 0.f}; \
        v2f aco = {fmaf(xv, wxo, bo_), 0.f}; \
        DO(0, hrd) DO(1, hrd) DO(2, hrd) DO(3, hrd) \
        const float ai = rsum8(aci.x + aci.y); \
        const float af = rsum8(acf.x + acf.y); \
        const float ag = rsum8(acg.x + acg.y); \
        const float ao = rsum8(aco.x + aco.y); \
        const float ig  = sigf(ai); \
        const float fg  = sigf(af); \
        const float gg2 = tanhf_fast(ag); \
        const float og  = sigf(ao); \
        c = fmaf(fg, c, ig * gg2); \
        const float hn = og * tanhf_fast(c); \
        if (lead) ((float*)hwr)[widx] = hn; \
        __syncthreads(); }

    const int Teven = T & ~1;
    for (int step = 0; step < Teven; step += 2) {
        STEP(hA, hB, step)
        STEP(hB, hA, step + 1)
    }
    if (T & 1) { STEP(hA, hB, T - 1) }
    const float* hf = (T & 1) ? (const float*)hB : (const float*)hA;
#undef STEP
#undef DO

    // Final linear: out = dot(W_lin, h_T) + b_lin (wave 0).
    if (t < 64) {
        const int e0 = t, e1 = t + 64;
        const int i0 = 32 * ((e0 & 15) >> 2) + 4 * (e0 >> 4) + (e0 & 3);
        const int i1 = 32 * ((e1 & 15) >> 2) + 4 * (e1 >> 4) + (e1 & 3);
        float v = Wlin[e0] * hf[i0] + Wlin[e1] * hf[i1];
        #pragma unroll
        for (int off = 32; off >= 1; off >>= 1) v += __shfl_down(v, off);
        if (t == 0) out[0] = v + blin[0];
    }
}

extern "C" void kernel_launch(void* const* d_in, const int* in_sizes, int n_in,
                              void* d_out, int out_size, void* d_ws, size_t ws_size,
                              hipStream_t stream) {
    const float* x    = (const float*)d_in[0];
    const float* Wih  = (const float*)d_in[1];
    const float* Whh  = (const float*)d_in[2];
    const float* bih  = (const float*)d_in[3];
    const float* bhh  = (const float*)d_in[4];
    const float* Wlin = (const float*)d_in[5];
    const float* blin = (const float*)d_in[6];
    const float* h0   = (const float*)d_in[7];
    const float* c0   = (const float*)d_in[8];
    float* out = (float*)d_out;
    const int T = in_sizes[0];

    lstm_seq_kernel<<<1, 1024, 0, stream>>>(x, Wih, Whh, bih, bhh, Wlin, blin,
                                            h0, c0, out, T);
}

// Round 11
// 5477.194 us; speedup vs baseline: 1.1865x; 1.1865x over previous
//
#include <hip/hip_runtime.h>

#define TMAX 8192
#define H 128

// rcp-based activations (v_rcp_f32, ~1 ulp) — proven win (round 7).
__device__ __forceinline__ float sigf(float x) {
    return __builtin_amdgcn_rcpf(1.f + __expf(-x));
}
__device__ __forceinline__ float tanhf_fast(float x) {
    return fmaf(2.f, __builtin_amdgcn_rcpf(1.f + __expf(-2.f * x)), -1.f);
}

// Sum across an aligned 8-lane group, all VALU DPP (no DS pipe):
// xor1 (quad_perm 0xB1) + xor2 (quad_perm 0x4E) + xor7 (row_half_mirror 0x141).
// {1,2,7} generate the 8-group, so 3 butterfly stages give the full sum in
// every lane.
__device__ __forceinline__ float rsum8(float v) {
    int s = __builtin_amdgcn_update_dpp(0, __float_as_int(v), 0xB1, 0xF, 0xF, true);
    v += __int_as_float(s);
    s = __builtin_amdgcn_update_dpp(0, __float_as_int(v), 0x4E, 0xF, 0xF, true);
    v += __int_as_float(s);
    s = __builtin_amdgcn_update_dpp(0, __float_as_int(v), 0x141, 0xF, 0xF, true);
    v += __int_as_float(s);
    return v;
}

// One block, 1024 threads = 16 waves (4/SIMD).
// Thread t: h-element j = t>>3, k-slice o = t&7 (lanes 8m..8m+7 share j).
// Owns all 4 gate rows {j, j+128, j+256, j+384} x 16-wide slice = 64 weights.
//
// ROUND 11 synthesis of rounds 0-10:
//  - SCALAR v_fma_f32 only: VOP3 can source AGPR-parked weights at zero cost
//    (R0: 91 inst/wave); VOP3P v_pk_fma_f32 cannot — every packed use forced
//    a v_accvgpr_read, erasing the 2x win (R8/R9/R10: 211-252 inst/wave).
//  - 4 waves/SIMD for latency hiding (R10: busy 74%->89%).
//  - Distributed redundant activations + DPP reduce: no serialized act phase
//    (R0's weakness), no DS-pipe shuffles, one barrier per step.
__attribute__((amdgpu_waves_per_eu(4, 4)))
__global__ __launch_bounds__(1024)
void lstm_seq_kernel(const float* __restrict__ x,
                     const float* __restrict__ Wih,
                     const float* __restrict__ Whh,
                     const float* __restrict__ bih,
                     const float* __restrict__ bhh,
                     const float* __restrict__ Wlin,
                     const float* __restrict__ blin,
                     const float* __restrict__ h0,
                     const float* __restrict__ c0,
                     float* __restrict__ out,
                     int T)
{
    __shared__ float  x_s[TMAX];      // 32 KB
    // Interleaved h (float4 units): slot(n,o) = n*8 + o holds h[16o+4n .. +3].
    // Element e -> float index 32*((e&15)>>2) + 4*(e>>4) + (e&3).
    // A wave's 8 o-groups read slots {n*8+o}: banks 4o..4o+3 -> disjoint,
    // same-o lanes broadcast: conflict-free.
    __shared__ float4 hA[32], hB[32];

    const int t = threadIdx.x;        // 0..1023
    const int j = t >> 3;             // h element 0..127
    const int o = t & 7;              // k-slice

    for (int idx = t; idx < T; idx += 1024) x_s[idx] = x[idx];

    // Weights: rows j, j+128, j+256, j+384; cols 16o..16o+15 (4 float4 each).
    // Plain loads + unrolled const indices = R0's proven codegen path.
    float4 wI[4], wF[4], wG[4], wO[4];
    {
        const float4* pi = (const float4*)(Whh + (j      ) * H + o * 16);
        const float4* pf = (const float4*)(Whh + (j + 128) * H + o * 16);
        const float4* pg = (const float4*)(Whh + (j + 256) * H + o * 16);
        const float4* po = (const float4*)(Whh + (j + 384) * H + o * 16);
        #pragma unroll
        for (int n = 0; n < 4; ++n) { wI[n] = pi[n]; wF[n] = pf[n]; wG[n] = pg[n]; wO[n] = po[n]; }
    }

    // x-weight and bias folded into slice 0's partial.
    const bool lead = (o == 0);
    const float wxi = lead ? Wih[j      ] : 0.f;
    const float wxf = lead ? Wih[j + 128] : 0.f;
    const float wxg = lead ? Wih[j + 256] : 0.f;
    const float wxo = lead ? Wih[j + 384] : 0.f;
    const float bi_ = lead ? bih[j      ] + bhh[j      ] : 0.f;
    const float bf_ = lead ? bih[j + 128] + bhh[j + 128] : 0.f;
    const float bg_ = lead ? bih[j + 256] + bhh[j + 256] : 0.f;
    const float bo_ = lead ? bih[j + 384] + bhh[j + 384] : 0.f;

    float c = c0[j];                  // replicated across the 8 lanes of j's group

    if (t < H) {
        const int fi = 32 * ((t & 15) >> 2) + 4 * (t >> 4) + (t & 3);
        ((float*)hA)[fi] = h0[t];
    }
    const int widx = 32 * ((j & 15) >> 2) + 4 * (j >> 4) + (j & 3);
    __syncthreads();

#define DO(n, hrd) { \
        const float4 h4 = hrd[n * 8 + o]; \
        ai = fmaf(wI[n].x, h4.x, ai); ai = fmaf(wI[n].y, h4.y, ai); \
        ai = fmaf(wI[n].z, h4.z, ai); ai = fmaf(wI[n].w, h4.w, ai); \
        af = fmaf(wF[n].x, h4.x, af); af = fmaf(wF[n].y, h4.y, af); \
        af = fmaf(wF[n].z, h4.z, af); af = fmaf(wF[n].w, h4.w, af); \
        ag = fmaf(wG[n].x, h4.x, ag); ag = fmaf(wG[n].y, h4.y, ag); \
        ag = fmaf(wG[n].z, h4.z, ag); ag = fmaf(wG[n].w, h4.w, ag); \
        ao = fmaf(wO[n].x, h4.x, ao); ao = fmaf(wO[n].y, h4.y, ao); \
        ao = fmaf(wO[n].z, h4.z, ao); ao = fmaf(wO[n].w, h4.w, ao); }

#define STEP(hrd, hwr, sidx) { \
        const float xv = x_s[sidx]; \
        float ai = fmaf(xv, wxi, bi_); \
        float af = fmaf(xv, wxf, bf_); \
        float ag = fmaf(xv, wxg, bg_); \
        float ao = fmaf(xv, wxo, bo_); \
        DO(0, hrd) DO(1, hrd) DO(2, hrd) DO(3, hrd) \
        ai = rsum8(ai); af = rsum8(af); ag = rsum8(ag); ao = rsum8(ao); \
        const float ig  = sigf(ai); \
        const float fg  = sigf(af); \
        const float gg2 = tanhf_fast(ag); \
        const float og  = sigf(ao); \
        c = fmaf(fg, c, ig * gg2); \
        const float hn = og * tanhf_fast(c); \
        if (lead) ((float*)hwr)[widx] = hn; \
        __syncthreads(); }

    const int Teven = T & ~1;
    for (int step = 0; step < Teven; step += 2) {
        STEP(hA, hB, step)
        STEP(hB, hA, step + 1)
    }
    if (T & 1) { STEP(hA, hB, T - 1) }
    const float* hf = (T & 1) ? (const float*)hB : (const float*)hA;
#undef STEP
#undef DO

    // Final linear: out = dot(W_lin, h_T) + b_lin (wave 0).
    if (t < 64) {
        const int e0 = t, e1 = t + 64;
        const int i0 = 32 * ((e0 & 15) >> 2) + 4 * (e0 >> 4) + (e0 & 3);
        const int i1 = 32 * ((e1 & 15) >> 2) + 4 * (e1 >> 4) + (e1 & 3);
        float v = Wlin[e0] * hf[i0] + Wlin[e1] * hf[i1];
        #pragma unroll
        for (int off = 32; off >= 1; off >>= 1) v += __shfl_down(v, off);
        if (t == 0) out[0] = v + blin[0];
    }
}

extern "C" void kernel_launch(void* const* d_in, const int* in_sizes, int n_in,
                              void* d_out, int out_size, void* d_ws, size_t ws_size,
                              hipStream_t stream) {
    const float* x    = (const float*)d_in[0];
    const float* Wih  = (const float*)d_in[1];
    const float* Whh  = (const float*)d_in[2];
    const float* bih  = (const float*)d_in[3];
    const float* bhh  = (const float*)d_in[4];
    const float* Wlin = (const float*)d_in[5];
    const float* blin = (const float*)d_in[6];
    const float* h0   = (const float*)d_in[7];
    const float* c0   = (const float*)d_in[8];
    float* out = (float*)d_out;
    const int T = in_sizes[0];

    lstm_seq_kernel<<<1, 1024, 0, stream>>>(x, Wih, Whh, bih, bhh, Wlin, blin,
                                            h0, c0, out, T);
}

// Round 12
// 5254.020 us; speedup vs baseline: 1.2369x; 1.0425x over previous
//
#include <hip/hip_runtime.h>

#define TMAX 8192
#define H 128

typedef float  f32x4 __attribute__((ext_vector_type(4)));
typedef short  s16x8 __attribute__((ext_vector_type(8)));
typedef unsigned short ushort_t;

__device__ __forceinline__ float sigf(float x) {
    return __builtin_amdgcn_rcpf(1.f + __expf(-x));
}
__device__ __forceinline__ float tanhf_fast(float x) {
    return fmaf(2.f, __builtin_amdgcn_rcpf(1.f + __expf(-2.f * x)), -1.f);
}
// round-to-nearest-even bf16 (ushort)
__device__ __forceinline__ unsigned short bf16_rne(float f) {
    unsigned int u = __float_as_uint(f);
    u += 0x7FFFu + ((u >> 16) & 1u);
    return (unsigned short)(u >> 16);
}
__device__ __forceinline__ float bf16f(unsigned short s) {
    return __uint_as_float(((unsigned int)s) << 16);
}

// One block, 512 threads = 8 waves (2/SIMD).
//
// ROUND 12: matvec on the MATRIX pipe. 12 rounds proved the gfx950 RA parks
// long-lived weights in AGPRs and VALU cannot source AGPRs (R5 assembler
// reject) -> every VALU weight-use pays a v_accvgpr_read copy. MFMA reads
// AGPRs natively: store W as bf16 hi/lo A-fragments (exact 2-term split),
// h replicated across all 16 B-cols (makes every lane hold 4 row-results AND
// makes the scheme immune to operand-order/k-permutation conventions).
// M-tile row order [4 gates x 4 j] => C reg r = gate r of one j per lane:
// activations fully in-register, 1 barrier/step, h fed back as bf16 via LDS.
__attribute__((amdgpu_waves_per_eu(2, 2)))
__global__ __launch_bounds__(512)
void lstm_seq_kernel(const float* __restrict__ x,
                     const float* __restrict__ Wih,
                     const float* __restrict__ Whh,
                     const float* __restrict__ bih,
                     const float* __restrict__ bhh,
                     const float* __restrict__ Wlin,
                     const float* __restrict__ blin,
                     const float* __restrict__ h0,
                     const float* __restrict__ c0,
                     float* __restrict__ out,
                     int T)
{
    __shared__ float  x_s[TMAX];     // 32 KB
    __shared__ s16x8  hv[2][16];     // double-buffered h as 128 bf16, 16B-aligned

    const int t   = threadIdx.x;     // 0..511
    const int l   = t & 63;
    const int w   = t >> 6;          // wave 0..7
    const int m   = l & 15;          // A row-within-tile / C col
    const int g16 = l >> 4;          // k-group / C row-group

    for (int idx = t; idx < T; idx += 512) x_s[idx] = x[idx];

    // ---- A fragments: Whh split exactly into bf16 hi + lo ----
    // Within-tile row m -> gate m&3, jj m>>2; tile tau covers j = w*16+tau*4+jj.
    // Elem i -> K = kap*32 + g16*8 + i (same k-map used for B: any consistent
    // permutation yields the same dot product).
    s16x8 Ahi[4][4], Alo[4][4];
    #pragma unroll
    for (int tau = 0; tau < 4; ++tau) {
        const int R = (m & 3) * H + w * 16 + tau * 4 + (m >> 2);
        const float* row = Whh + R * H;
        #pragma unroll
        for (int kap = 0; kap < 4; ++kap) {
            const int K0 = kap * 32 + g16 * 8;
            s16x8 hi, lo;
            #pragma unroll
            for (int i = 0; i < 8; ++i) {
                const float f = row[K0 + i];
                const unsigned short hs = bf16_rne(f);
                const float res = f - bf16f(hs);   // exact residual
                hi[i] = (short)hs;
                lo[i] = (short)bf16_rne(res);
            }
            Ahi[tau][kap] = hi;
            Alo[tau][kap] = lo;
        }
    }

    // Accumulator init = bias (per tile tau, gate r; row R = r*128 + j(tau,g16)).
    float bini[4][4];
    #pragma unroll
    for (int tau = 0; tau < 4; ++tau)
        #pragma unroll
        for (int r = 0; r < 4; ++r) {
            const int R = r * H + w * 16 + tau * 4 + g16;
            bini[tau][r] = bih[R] + bhh[R];
        }

    // Activation side: col-group picks which tile's j this lane finishes.
    const int tsel  = (l >> 2) & 3;
    const int jproc = w * 16 + tsel * 4 + g16;
    const float wx0 = Wih[0 * H + jproc];
    const float wx1 = Wih[1 * H + jproc];
    const float wx2 = Wih[2 * H + jproc];
    const float wx3 = Wih[3 * H + jproc];
    float c = c0[jproc];                 // 4-way redundant (bit-identical math)
    const bool writer = ((l & 3) == 0);  // one col per (tile,jj) writes h

    if (t < H) ((ushort_t*)hv[0])[t] = bf16_rne(h0[t]);
    __syncthreads();

#define MFMA(A, B, C) __builtin_amdgcn_mfma_f32_16x16x32_bf16((A), (B), (C), 0, 0, 0)
#define KSTEP(KAP, B) \
    a0 = MFMA(Ahi[0][KAP], B, a0); a0 = MFMA(Alo[0][KAP], B, a0); \
    a1 = MFMA(Ahi[1][KAP], B, a1); a1 = MFMA(Alo[1][KAP], B, a1); \
    a2 = MFMA(Ahi[2][KAP], B, a2); a2 = MFMA(Alo[2][KAP], B, a2); \
    a3 = MFMA(Ahi[3][KAP], B, a3); a3 = MFMA(Alo[3][KAP], B, a3);
#define SEL(K) ((tsel & 2) ? ((tsel & 1) ? a3[K] : a2[K]) \
                           : ((tsel & 1) ? a1[K] : a0[K]))

#define STEP(RD, WR, SIDX) { \
    const float xv = x_s[SIDX]; \
    const ushort_t* hr = (const ushort_t*)(RD); \
    const s16x8 B0 = *(const s16x8*)(hr +  0 + g16 * 8); \
    const s16x8 B1 = *(const s16x8*)(hr + 32 + g16 * 8); \
    const s16x8 B2 = *(const s16x8*)(hr + 64 + g16 * 8); \
    const s16x8 B3 = *(const s16x8*)(hr + 96 + g16 * 8); \
    f32x4 a0 = {bini[0][0], bini[0][1], bini[0][2], bini[0][3]}; \
    f32x4 a1 = {bini[1][0], bini[1][1], bini[1][2], bini[1][3]}; \
    f32x4 a2 = {bini[2][0], bini[2][1], bini[2][2], bini[2][3]}; \
    f32x4 a3 = {bini[3][0], bini[3][1], bini[3][2], bini[3][3]}; \
    KSTEP(0, B0) KSTEP(1, B1) KSTEP(2, B2) KSTEP(3, B3) \
    const float gi = fmaf(xv, wx0, SEL(0)); \
    const float gf = fmaf(xv, wx1, SEL(1)); \
    const float gg = fmaf(xv, wx2, SEL(2)); \
    const float go = fmaf(xv, wx3, SEL(3)); \
    const float ig = sigf(gi); \
    const float fg = sigf(gf); \
    const float g2 = tanhf_fast(gg); \
    const float og = sigf(go); \
    c = fmaf(fg, c, ig * g2); \
    const float hn = og * tanhf_fast(c); \
    if (writer) ((ushort_t*)(WR))[jproc] = bf16_rne(hn); \
    __syncthreads(); }

    const int Teven = T & ~1;
    for (int s = 0; s < Teven; s += 2) {
        STEP(hv[0], hv[1], s)
        STEP(hv[1], hv[0], s + 1)
    }
    if (T & 1) { STEP(hv[0], hv[1], T - 1) }
    const ushort_t* hf = (const ushort_t*)hv[T & 1];
#undef STEP
#undef SEL
#undef KSTEP
#undef MFMA

    // Final linear: out = dot(W_lin, h_T) + b_lin (wave 0).
    if (t < 64) {
        float v = Wlin[t] * bf16f(hf[t]) + Wlin[t + 64] * bf16f(hf[t + 64]);
        #pragma unroll
        for (int off = 32; off >= 1; off >>= 1) v += __shfl_down(v, off);
        if (t == 0) out[0] = v + blin[0];
    }
}

extern "C" void kernel_launch(void* const* d_in, const int* in_sizes, int n_in,
                              void* d_out, int out_size, void* d_ws, size_t ws_size,
                              hipStream_t stream) {
    const float* x    = (const float*)d_in[0];
    const float* Wih  = (const float*)d_in[1];
    const float* Whh  = (const float*)d_in[2];
    const float* bih  = (const float*)d_in[3];
    const float* bhh  = (const float*)d_in[4];
    const float* Wlin = (const float*)d_in[5];
    const float* blin = (const float*)d_in[6];
    const float* h0   = (const float*)d_in[7];
    const float* c0   = (const float*)d_in[8];
    float* out = (float*)d_out;
    const int T = in_sizes[0];

    lstm_seq_kernel<<<1, 512, 0, stream>>>(x, Wih, Whh, bih, bhh, Wlin, blin,
                                           h0, c0, out, T);
}

// Round 13
// 4332.203 us; speedup vs baseline: 1.5001x; 1.2128x over previous
//
#include <hip/hip_runtime.h>

#define TMAX 8192
#define H 128

typedef float  f32x4 __attribute__((ext_vector_type(4)));
typedef short  s16x8 __attribute__((ext_vector_type(8)));
typedef unsigned short ushort_t;

__device__ __forceinline__ float sigf(float x) {
    return __builtin_amdgcn_rcpf(1.f + __expf(-x));
}
__device__ __forceinline__ float tanhf_fast(float x) {
    return fmaf(2.f, __builtin_amdgcn_rcpf(1.f + __expf(-2.f * x)), -1.f);
}
__device__ __forceinline__ unsigned short bf16_rne(float f) {
    unsigned int u = __float_as_uint(f);
    u += 0x7FFFu + ((u >> 16) & 1u);
    return (unsigned short)(u >> 16);
}
__device__ __forceinline__ float bf16f(unsigned short s) {
    return __uint_as_float(((unsigned int)s) << 16);
}

// One block, 1024 threads = 16 waves (4/SIMD).
//
// ROUND 13: R12 hit the MATRIX-PIPE ROOFLINE for the hi/lo-split formulation:
// 256 MFMA/step x 4.85 cyc = 1242 cyc/step = 5.18 ms (measured 5.22; MfmaUtil
// 66% on the active CU). R12 also proved (absmax 0.0 with per-step bf16-h
// feedback) that the LSTM contracts ~2^-9 gate perturbations completely.
// So: drop the lo residual (W plain bf16) -> 128 MFMA/step, floor 620 cyc
// (2.6 ms); spread over 16 waves (4/SIMD) to hide DS/act/barrier latency;
// bias rides as the persistent C-input of each chain's first MFMA (no
// per-step accumulator init).
__attribute__((amdgpu_waves_per_eu(4, 4)))
__global__ __launch_bounds__(1024)
void lstm_seq_kernel(const float* __restrict__ x,
                     const float* __restrict__ Wih,
                     const float* __restrict__ Whh,
                     const float* __restrict__ bih,
                     const float* __restrict__ bhh,
                     const float* __restrict__ Wlin,
                     const float* __restrict__ blin,
                     const float* __restrict__ h0,
                     const float* __restrict__ c0,
                     float* __restrict__ out,
                     int T)
{
    __shared__ float  x_s[TMAX];     // 32 KB
    __shared__ s16x8  hv[2][16];     // double-buffered h as 128 bf16

    const int t   = threadIdx.x;     // 0..1023
    const int l   = t & 63;
    const int w   = t >> 6;          // wave 0..15
    const int m   = l & 15;          // A row-within-tile / C col
    const int g16 = l >> 4;          // k-group / C row-group

    for (int idx = t; idx < T; idx += 1024) x_s[idx] = x[idx];

    // ---- A fragments: Whh as plain bf16 (no residual) ----
    // Tile tau (0..1): within-tile row m -> gate m&3, jj m>>2;
    // covers rows R = (m&3)*H + w*8 + tau*4 + (m>>2).
    // Elem i -> K = kap*32 + g16*8 + i (same k-map as B; layout verified
    // bit-exact in R12).
    s16x8 Abf[2][4];
    #pragma unroll
    for (int tau = 0; tau < 2; ++tau) {
        const int R = (m & 3) * H + w * 8 + tau * 4 + (m >> 2);
        const float* row = Whh + R * H;
        #pragma unroll
        for (int kap = 0; kap < 4; ++kap) {
            const int K0 = kap * 32 + g16 * 8;
            s16x8 v;
            #pragma unroll
            for (int i = 0; i < 8; ++i) v[i] = (short)bf16_rne(row[K0 + i]);
            Abf[tau][kap] = v;
        }
    }

    // Persistent bias vectors: C-input of each chain's first MFMA.
    // C reg r = gate r of j = w*8 + tau*4 + g16 (R12-verified C/D map).
    f32x4 bini[2];
    #pragma unroll
    for (int tau = 0; tau < 2; ++tau)
        #pragma unroll
        for (int r = 0; r < 4; ++r) {
            const int R = r * H + w * 8 + tau * 4 + g16;
            bini[tau][r] = bih[R] + bhh[R];
        }

    // Activation side: col m finishes tile tsel = m&1 (8-way redundant).
    const int tsel  = m & 1;
    const int jproc = w * 8 + tsel * 4 + g16;
    const float wx0 = Wih[0 * H + jproc];
    const float wx1 = Wih[1 * H + jproc];
    const float wx2 = Wih[2 * H + jproc];
    const float wx3 = Wih[3 * H + jproc];
    float c = c0[jproc];
    const bool writer = (m < 2);      // m=0 -> tile 0, m=1 -> tile 1

    if (t < H) ((ushort_t*)hv[0])[t] = bf16_rne(h0[t]);
    __syncthreads();

#define MFMA(A, B, C) __builtin_amdgcn_mfma_f32_16x16x32_bf16((A), (B), (C), 0, 0, 0)
#define SEL(K) (tsel ? a1[K] : a0[K])

#define STEP(RD, WR, SIDX) { \
    const float xv = x_s[SIDX]; \
    const ushort_t* hr = (const ushort_t*)(RD); \
    const s16x8 B0 = *(const s16x8*)(hr +  0 + g16 * 8); \
    const s16x8 B1 = *(const s16x8*)(hr + 32 + g16 * 8); \
    const s16x8 B2 = *(const s16x8*)(hr + 64 + g16 * 8); \
    const s16x8 B3 = *(const s16x8*)(hr + 96 + g16 * 8); \
    f32x4 a0 = MFMA(Abf[0][0], B0, bini[0]); \
    f32x4 a1 = MFMA(Abf[1][0], B0, bini[1]); \
    a0 = MFMA(Abf[0][1], B1, a0); \
    a1 = MFMA(Abf[1][1], B1, a1); \
    a0 = MFMA(Abf[0][2], B2, a0); \
    a1 = MFMA(Abf[1][2], B2, a1); \
    a0 = MFMA(Abf[0][3], B3, a0); \
    a1 = MFMA(Abf[1][3], B3, a1); \
    const float gi = fmaf(xv, wx0, SEL(0)); \
    const float gf = fmaf(xv, wx1, SEL(1)); \
    const float gg = fmaf(xv, wx2, SEL(2)); \
    const float go = fmaf(xv, wx3, SEL(3)); \
    const float ig = sigf(gi); \
    const float fg = sigf(gf); \
    const float g2 = tanhf_fast(gg); \
    const float og = sigf(go); \
    c = fmaf(fg, c, ig * g2); \
    const float hn = og * tanhf_fast(c); \
    if (writer) ((ushort_t*)(WR))[jproc] = bf16_rne(hn); \
    __syncthreads(); }

    const int Teven = T & ~1;
    for (int s = 0; s < Teven; s += 2) {
        STEP(hv[0], hv[1], s)
        STEP(hv[1], hv[0], s + 1)
    }
    if (T & 1) { STEP(hv[0], hv[1], T - 1) }
    const ushort_t* hf = (const ushort_t*)hv[T & 1];
#undef STEP
#undef SEL
#undef MFMA

    // Final linear: out = dot(W_lin, h_T) + b_lin (wave 0).
    if (t < 64) {
        float v = Wlin[t] * bf16f(hf[t]) + Wlin[t + 64] * bf16f(hf[t + 64]);
        #pragma unroll
        for (int off = 32; off >= 1; off >>= 1) v += __shfl_down(v, off);
        if (t == 0) out[0] = v + blin[0];
    }
}

extern "C" void kernel_launch(void* const* d_in, const int* in_sizes, int n_in,
                              void* d_out, int out_size, void* d_ws, size_t ws_size,
                              hipStream_t stream) {
    const float* x    = (const float*)d_in[0];
    const float* Wih  = (const float*)d_in[1];
    const float* Whh  = (const float*)d_in[2];
    const float* bih  = (const float*)d_in[3];
    const float* bhh  = (const float*)d_in[4];
    const float* Wlin = (const float*)d_in[5];
    const float* blin = (const float*)d_in[6];
    const float* h0   = (const float*)d_in[7];
    const float* c0   = (const float*)d_in[8];
    float* out = (float*)d_out;
    const int T = in_sizes[0];

    lstm_seq_kernel<<<1, 1024, 0, stream>>>(x, Wih, Whh, bih, bhh, Wlin, blin,
                                            h0, c0, out, T);
}

// Round 14
// 3613.371 us; speedup vs baseline: 1.7985x; 1.1989x over previous
//
#include <hip/hip_runtime.h>

#define TMAX 8192
#define H 128

typedef float  f32x4 __attribute__((ext_vector_type(4)));
typedef short  s16x8 __attribute__((ext_vector_type(8)));
typedef unsigned short ushort_t;

__device__ __forceinline__ float sigf(float x) {
    return __builtin_amdgcn_rcpf(1.f + __expf(-x));
}
__device__ __forceinline__ float tanhf_fast(float x) {
    return fmaf(2.f, __builtin_amdgcn_rcpf(1.f + __expf(-2.f * x)), -1.f);
}
__device__ __forceinline__ unsigned short bf16_rne(float f) {
    unsigned int u = __float_as_uint(f);
    u += 0x7FFFu + ((u >> 16) & 1u);
    return (unsigned short)(u >> 16);
}
__device__ __forceinline__ float bf16f(unsigned short s) {
    return __uint_as_float(((unsigned int)s) << 16);
}

// One block, 512 threads = 8 waves (2/SIMD) — R12's exact geometry.
//
// ROUND 14 = R12 minus the lo-residual MFMAs:
//  - R12 (hi/lo, 256 MFMA/step) ran AT its matrix-pipe floor (1242 cyc/step
//    predicted, 1274 measured) -> at 2 waves/SIMD all VALU/DS work hides
//    under the MFMA shadow.
//  - R13 (plain bf16 W) proved absmax 0.0 -> the lo term is unnecessary.
//  - R13's regression vs floor came from 4 waves/SIMD of activation VALU
//    (per-wave activation cost is constant, so VALU pressure scales with
//    waves/SIMD). Back to 2 waves/SIMD: VALU ~280 cyc < MFMA 621 cyc.
// Floor: 128 MFMA/step x 4.85 cyc = 621 cyc/step = 2.59 ms.
__attribute__((amdgpu_waves_per_eu(2, 2)))
__global__ __launch_bounds__(512)
void lstm_seq_kernel(const float* __restrict__ x,
                     const float* __restrict__ Wih,
                     const float* __restrict__ Whh,
                     const float* __restrict__ bih,
                     const float* __restrict__ bhh,
                     const float* __restrict__ Wlin,
                     const float* __restrict__ blin,
                     const float* __restrict__ h0,
                     const float* __restrict__ c0,
                     float* __restrict__ out,
                     int T)
{
    __shared__ float  x_s[TMAX];     // 32 KB
    __shared__ s16x8  hv[2][16];     // double-buffered h as 128 bf16

    const int t   = threadIdx.x;     // 0..511
    const int l   = t & 63;
    const int w   = t >> 6;          // wave 0..7
    const int m   = l & 15;          // A row-within-tile / C col
    const int g16 = l >> 4;          // k-group / C row-group

    for (int idx = t; idx < T; idx += 512) x_s[idx] = x[idx];

    // ---- A fragments: Whh as plain bf16 ----
    // Tile tau (0..3): within-tile row m -> gate m&3, jj m>>2;
    // covers rows R = (m&3)*H + w*16 + tau*4 + (m>>2).
    // Elem i -> K = kap*32 + g16*8 + i (k-map verified bit-exact in R12).
    s16x8 Abf[4][4];
    #pragma unroll
    for (int tau = 0; tau < 4; ++tau) {
        const int R = (m & 3) * H + w * 16 + tau * 4 + (m >> 2);
        const float* row = Whh + R * H;
        #pragma unroll
        for (int kap = 0; kap < 4; ++kap) {
            const int K0 = kap * 32 + g16 * 8;
            s16x8 v;
            #pragma unroll
            for (int i = 0; i < 8; ++i) v[i] = (short)bf16_rne(row[K0 + i]);
            Abf[tau][kap] = v;
        }
    }

    // Persistent bias: C-input of each chain's first MFMA.
    // C reg r = gate r of j = w*16 + tau*4 + g16 (R12-verified C/D map).
    f32x4 bini[4];
    #pragma unroll
    for (int tau = 0; tau < 4; ++tau)
        #pragma unroll
        for (int r = 0; r < 4; ++r) {
            const int R = r * H + w * 16 + tau * 4 + g16;
            bini[tau][r] = bih[R] + bhh[R];
        }

    // Activation side: col-group picks which tile's j this lane finishes.
    const int tsel  = (l >> 2) & 3;
    const int jproc = w * 16 + tsel * 4 + g16;
    const float wx0 = Wih[0 * H + jproc];
    const float wx1 = Wih[1 * H + jproc];
    const float wx2 = Wih[2 * H + jproc];
    const float wx3 = Wih[3 * H + jproc];
    float c = c0[jproc];                 // 4-way redundant (bit-identical math)
    const bool writer = ((l & 3) == 0);  // one col per (tile,jj) writes h

    if (t < H) ((ushort_t*)hv[0])[t] = bf16_rne(h0[t]);
    __syncthreads();

#define MFMA(A, B, C) __builtin_amdgcn_mfma_f32_16x16x32_bf16((A), (B), (C), 0, 0, 0)
#define SEL(K) ((tsel & 2) ? ((tsel & 1) ? a3[K] : a2[K]) \
                           : ((tsel & 1) ? a1[K] : a0[K]))

#define STEP(RD, WR, SIDX) { \
    const float xv = x_s[SIDX]; \
    const ushort_t* hr = (const ushort_t*)(RD); \
    const s16x8 B0 = *(const s16x8*)(hr +  0 + g16 * 8); \
    const s16x8 B1 = *(const s16x8*)(hr + 32 + g16 * 8); \
    const s16x8 B2 = *(const s16x8*)(hr + 64 + g16 * 8); \
    const s16x8 B3 = *(const s16x8*)(hr + 96 + g16 * 8); \
    f32x4 a0 = MFMA(Abf[0][0], B0, bini[0]); \
    f32x4 a1 = MFMA(Abf[1][0], B0, bini[1]); \
    f32x4 a2 = MFMA(Abf[2][0], B0, bini[2]); \
    f32x4 a3 = MFMA(Abf[3][0], B0, bini[3]); \
    a0 = MFMA(Abf[0][1], B1, a0); \
    a1 = MFMA(Abf[1][1], B1, a1); \
    a2 = MFMA(Abf[2][1], B1, a2); \
    a3 = MFMA(Abf[3][1], B1, a3); \
    a0 = MFMA(Abf[0][2], B2, a0); \
    a1 = MFMA(Abf[1][2], B2, a1); \
    a2 = MFMA(Abf[2][2], B2, a2); \
    a3 = MFMA(Abf[3][2], B2, a3); \
    a0 = MFMA(Abf[0][3], B3, a0); \
    a1 = MFMA(Abf[1][3], B3, a1); \
    a2 = MFMA(Abf[2][3], B3, a2); \
    a3 = MFMA(Abf[3][3], B3, a3); \
    const float gi = fmaf(xv, wx0, SEL(0)); \
    const float gf = fmaf(xv, wx1, SEL(1)); \
    const float gg = fmaf(xv, wx2, SEL(2)); \
    const float go = fmaf(xv, wx3, SEL(3)); \
    const float ig = sigf(gi); \
    const float fg = sigf(gf); \
    const float g2 = tanhf_fast(gg); \
    const float og = sigf(go); \
    c = fmaf(fg, c, ig * g2); \
    const float hn = og * tanhf_fast(c); \
    if (writer) ((ushort_t*)(WR))[jproc] = bf16_rne(hn); \
    __syncthreads(); }

    const int Teven = T & ~1;
    for (int s = 0; s < Teven; s += 2) {
        STEP(hv[0], hv[1], s)
        STEP(hv[1], hv[0], s + 1)
    }
    if (T & 1) { STEP(hv[0], hv[1], T - 1) }
    const ushort_t* hf = (const ushort_t*)hv[T & 1];
#undef STEP
#undef SEL
#undef MFMA

    // Final linear: out = dot(W_lin, h_T) + b_lin (wave 0).
    if (t < 64) {
        float v = Wlin[t] * bf16f(hf[t]) + Wlin[t + 64] * bf16f(hf[t + 64]);
        #pragma unroll
        for (int off = 32; off >= 1; off >>= 1) v += __shfl_down(v, off);
        if (t == 0) out[0] = v + blin[0];
    }
}

extern "C" void kernel_launch(void* const* d_in, const int* in_sizes, int n_in,
                              void* d_out, int out_size, void* d_ws, size_t ws_size,
                              hipStream_t stream) {
    const float* x    = (const float*)d_in[0];
    const float* Wih  = (const float*)d_in[1];
    const float* Whh  = (const float*)d_in[2];
    const float* bih  = (const float*)d_in[3];
    const float* bhh  = (const float*)d_in[4];
    const float* Wlin = (const float*)d_in[5];
    const float* blin = (const float*)d_in[6];
    const float* h0   = (const float*)d_in[7];
    const float* c0   = (const float*)d_in[8];
    float* out = (float*)d_out;
    const int T = in_sizes[0];

    lstm_seq_kernel<<<1, 512, 0, stream>>>(x, Wih, Whh, bih, bhh, Wlin, blin,
                                           h0, c0, out, T);
}

// Round 15
// 3033.184 us; speedup vs baseline: 2.1425x; 1.1913x over previous
//
#include <hip/hip_runtime.h>

#define TMAX 8192
#define H 128

typedef int   i32x4 __attribute__((ext_vector_type(4)));

__device__ __forceinline__ float sigf(float x) {
    return __builtin_amdgcn_rcpf(1.f + __expf(-x));
}
__device__ __forceinline__ float tanhf_fast(float x) {
    return fmaf(2.f, __builtin_amdgcn_rcpf(1.f + __expf(-2.f * x)), -1.f);
}

// One block, 512 threads = 8 waves (2/SIMD) — R14 geometry.
//
// ROUND 15: int8 MFMA (mfma_i32_16x16x64_i8, 2x bf16 rate, K=64):
//  - matrix work halves: 128 -> 64 MFMA/step/CU (326 vs 515 cyc/SIMD), and
//    chains shorten 4 -> 2.
//  - W int8 per-row scaled (rowmax/127, static, one-time LDS table); h int8
//    at fixed scale 127 (tanh-bounded |h|<1). Int dot is EXACT; descale is
//    one fma/gate. Error class ~2-4x the bf16 case that gave absmax 0.0
//    (R13) -> predicted absmax <= 2e-3.
//  - k-map immunity: B cols are replicated h, and A/B are packed with the
//    SAME (g16, elem)->k map, so any consistent permutation yields the exact
//    dot (proven bit-exact in R12 for bf16; same argument here).
__attribute__((amdgpu_waves_per_eu(2, 2)))
__global__ __launch_bounds__(512)
void lstm_seq_kernel(const float* __restrict__ x,
                     const float* __restrict__ Wih,
                     const float* __restrict__ Whh,
                     const float* __restrict__ bih,
                     const float* __restrict__ bhh,
                     const float* __restrict__ Wlin,
                     const float* __restrict__ blin,
                     const float* __restrict__ h0,
                     const float* __restrict__ c0,
                     float* __restrict__ out,
                     int T)
{
    __shared__ float  x_s[TMAX];    // 32 KB
    __shared__ float  srow[512];    // per-row |W|max (2 KB)
    __shared__ i32x4  hv4[2][8];    // double-buffered h as 128 int8 (2x128 B)

    const int t   = threadIdx.x;    // 0..511
    const int l   = t & 63;
    const int w   = t >> 6;         // wave 0..7
    const int m   = l & 15;         // A row-within-tile / C col
    const int g16 = l >> 4;         // k-group / C row-group

    for (int idx = t; idx < T; idx += 512) x_s[idx] = x[idx];

    // ---- per-row absmax of Whh (one row per thread, one-time) ----
    {
        const float* row = Whh + t * H;
        float mx = 0.f;
        for (int k = 0; k < H; ++k) mx = fmaxf(mx, fabsf(row[k]));
        srow[t] = fmaxf(mx, 1e-30f);
    }
    __syncthreads();

    // ---- pack A fragments: int8, per-row scale 127/rowmax ----
    // Tile tau: within-tile row m -> gate m&3, jj m>>2;
    // R = (m&3)*H + w*16 + tau*4 + (m>>2). Elem i (0..15) of chunk c:
    // K = c*64 + g16*16 + i, byte i of the 4-dword fragment.
    i32x4 Aq[4][2];
    #pragma unroll
    for (int tau = 0; tau < 4; ++tau) {
        const int R = (m & 3) * H + w * 16 + tau * 4 + (m >> 2);
        const float inv = 127.f / srow[R];
        const float* rp = Whh + R * H;
        #pragma unroll
        for (int c = 0; c < 2; ++c) {
            int wd0 = 0, wd1 = 0, wd2 = 0, wd3 = 0;
            #pragma unroll
            for (int i = 0; i < 4; ++i) {
                const int base = c * 64 + g16 * 16;
                wd0 |= (((int)rintf(rp[base +  0 + i] * inv)) & 0xFF) << (i * 8);
                wd1 |= (((int)rintf(rp[base +  4 + i] * inv)) & 0xFF) << (i * 8);
                wd2 |= (((int)rintf(rp[base +  8 + i] * inv)) & 0xFF) << (i * 8);
                wd3 |= (((int)rintf(rp[base + 12 + i] * inv)) & 0xFF) << (i * 8);
            }
            Aq[tau][c] = (i32x4){wd0, wd1, wd2, wd3};
        }
    }

    // ---- epilogue constants (fp32 path) ----
    const int tsel  = (l >> 2) & 3;
    const int jproc = w * 16 + tsel * 4 + g16;
    // gate r of jproc came from A-row r*H + jproc; descale = rowmax/(127*127).
    const float sc0 = srow[0 * H + jproc] * (1.f / 16129.f);
    const float sc1 = srow[1 * H + jproc] * (1.f / 16129.f);
    const float sc2 = srow[2 * H + jproc] * (1.f / 16129.f);
    const float sc3 = srow[3 * H + jproc] * (1.f / 16129.f);
    const float wx0 = Wih[0 * H + jproc];
    const float wx1 = Wih[1 * H + jproc];
    const float wx2 = Wih[2 * H + jproc];
    const float wx3 = Wih[3 * H + jproc];
    const float b0  = bih[0 * H + jproc] + bhh[0 * H + jproc];
    const float b1  = bih[1 * H + jproc] + bhh[1 * H + jproc];
    const float b2  = bih[2 * H + jproc] + bhh[2 * H + jproc];
    const float b3  = bih[3 * H + jproc] + bhh[3 * H + jproc];
    float c = c0[jproc];                 // 4-way redundant (bit-identical math)
    const bool writer = ((l & 3) == 0);  // one col per (tile,jj) writes h

    const i32x4 zeroC = {0, 0, 0, 0};    // persistent zero C-in

    if (t < H) {
        ((signed char*)hv4[0])[t] = (signed char)(int)rintf(h0[t] * 127.f);
    }
    __syncthreads();

#define MFMA(A, B, C) __builtin_amdgcn_mfma_i32_16x16x64_i8((A), (B), (C), 0, 0, 0)
#define SEL(K) ((tsel & 2) ? ((tsel & 1) ? a3[K] : a2[K]) \
                           : ((tsel & 1) ? a1[K] : a0[K]))

#define STEP(RD, WR, SIDX) { \
    const float xv = x_s[SIDX]; \
    const i32x4 B0 = hv4[RD][g16]; \
    const i32x4 B1 = hv4[RD][4 + g16]; \
    i32x4 a0 = MFMA(Aq[0][0], B0, zeroC); \
    i32x4 a1 = MFMA(Aq[1][0], B0, zeroC); \
    i32x4 a2 = MFMA(Aq[2][0], B0, zeroC); \
    i32x4 a3 = MFMA(Aq[3][0], B0, zeroC); \
    a0 = MFMA(Aq[0][1], B1, a0); \
    a1 = MFMA(Aq[1][1], B1, a1); \
    a2 = MFMA(Aq[2][1], B1, a2); \
    a3 = MFMA(Aq[3][1], B1, a3); \
    const float gi = fmaf((float)SEL(0), sc0, fmaf(xv, wx0, b0)); \
    const float gf = fmaf((float)SEL(1), sc1, fmaf(xv, wx1, b1)); \
    const float gg = fmaf((float)SEL(2), sc2, fmaf(xv, wx2, b2)); \
    const float go = fmaf((float)SEL(3), sc3, fmaf(xv, wx3, b3)); \
    const float ig = sigf(gi); \
    const float fg = sigf(gf); \
    const float g2 = tanhf_fast(gg); \
    const float og = sigf(go); \
    c = fmaf(fg, c, ig * g2); \
    const float hn = og * tanhf_fast(c); \
    if (writer) ((signed char*)hv4[WR])[jproc] = (signed char)(int)rintf(hn * 127.f); \
    __syncthreads(); }

    const int Teven = T & ~1;
    for (int s = 0; s < Teven; s += 2) {
        STEP(0, 1, s)
        STEP(1, 0, s + 1)
    }
    if (T & 1) { STEP(0, 1, T - 1) }
    const signed char* hf = (const signed char*)hv4[T & 1];
#undef STEP
#undef SEL
#undef MFMA

    // Final linear: out = dot(W_lin, h_T) + b_lin (wave 0).
    if (t < 64) {
        const float h0f = (float)hf[t]      * (1.f / 127.f);
        const float h1f = (float)hf[t + 64] * (1.f / 127.f);
        float v = Wlin[t] * h0f + Wlin[t + 64] * h1f;
        #pragma unroll
        for (int off = 32; off >= 1; off >>= 1) v += __shfl_down(v, off);
        if (t == 0) out[0] = v + blin[0];
    }
}

extern "C" void kernel_launch(void* const* d_in, const int* in_sizes, int n_in,
                              void* d_out, int out_size, void* d_ws, size_t ws_size,
                              hipStream_t stream) {
    const float* x    = (const float*)d_in[0];
    const float* Wih  = (const float*)d_in[1];
    const float* Whh  = (const float*)d_in[2];
    const float* bih  = (const float*)d_in[3];
    const float* bhh  = (const float*)d_in[4];
    const float* Wlin = (const float*)d_in[5];
    const float* blin = (const float*)d_in[6];
    const float* h0   = (const float*)d_in[7];
    const float* c0   = (const float*)d_in[8];
    float* out = (float*)d_out;
    const int T = in_sizes[0];

    lstm_seq_kernel<<<1, 512, 0, stream>>>(x, Wih, Whh, bih, bhh, Wlin, blin,
                                           h0, c0, out, T);
}